// Round 11
// baseline (88.026 us; speedup 1.0000x reference)
//
#include <hip/hip_runtime.h>
#include <math.h>

// pred: (1,16,384,384) fp32, labels int32 same shape, area fp32[256]
constexpr int ZN = 16, YN = 384, XN = 384;
constexpr int NZ = 17, NY = 385, NX = 385;   // node grid
constexpr int NP = NY * NX;                  // 148225 nodes per z-slab
constexpr int NPAIRS = 193;                  // y-pair index u: node rows 2u, 2u+1
constexpr int NWAVES = NZ * NPAIRS;          // 3281 waves
constexpr int BLOCKS = (NWAVES + 3) / 4;     // 821 blocks x 4 waves

typedef float F2 __attribute__((ext_vector_type(2)));
typedef int   I2 __attribute__((ext_vector_type(2)));

__device__ __forceinline__ float sigm(float p) {
    return __fdividef(1.f, 1.f + __expf(-p));
}

__global__ __launch_bounds__(256) void sd_main(
        const float* __restrict__ pred,
        const int*   __restrict__ labels,
        const float* __restrict__ area,
        float*       __restrict__ partial)   // [num BLOCKS][den BLOCKS][vol BLOCKS]
{
    // Re-indexed LUT: idx = (own_col_nibble << 4) | prev_col_nibble,
    // nibble bit r = 2dz+dy (orig corner k = dz*4+dy*2+dx = 2r+dx; dx=0 prev, 1 own)
    __shared__ float s_area[256];
    {
        const int t = threadIdx.x;
        const int own = t >> 4, prv = t & 15;
        int code = 0;
#pragma unroll
        for (int r = 0; r < 4; ++r)
            code |= (((prv >> r) & 1) << (2 * r)) | (((own >> r) & 1) << (2 * r + 1));
        s_area[t] = area[code];
    }
    __syncthreads();

    const int lane = threadIdx.x & 63;
    const int wid = __builtin_amdgcn_readfirstlane(blockIdx.x * 4 + (threadIdx.x >> 6));

    float num = 0.f, den = 0.f, vol = 0.f;

    if (wid < NWAVES) {
        const int z = wid / NPAIRS;          // node z: 0..16 (scalar)
        const int u = wid - z * NPAIRS;      // y-pair: 0..192 (scalar)
        const bool hasB = (u < 192);         // node row 2u+1 exists

        // voxel rows r = zi*3 + gi: zz = z-1+zi, yy = 2u-1+gi
        bool rv[6]; int cbase[6];
#pragma unroll
        for (int zi = 0; zi < 2; ++zi)
#pragma unroll
            for (int gi = 0; gi < 3; ++gi) {
                const int r = zi * 3 + gi;
                const int zz = z - 1 + zi, yy = 2 * u - 1 + gi;
                rv[r] = ((unsigned)zz < (unsigned)ZN) & ((unsigned)yy < (unsigned)YN);
                const int zc = min(max(zz, 0), ZN - 1);
                const int yc = min(max(yy, 0), YN - 1);
                cbase[r] = (zc * YN + yc) * XN;   // clamped -> loads always in-bounds
            }

        // node-row A nibble from 6-bit field L (bit r): rows {0,1,3,4}; B: {1,2,4,5}
        auto nibA = [](int b) { return (b & 3) | ((b >> 1) & 12); };
        auto nibB = [](int b) { return ((b >> 1) & 3) | ((b >> 2) & 12); };

        auto node = [&](const float* sp, float qp, int lp, int pp,
                        const float* so, float qo, int lo, int po) {
            const int idxL = (lo << 4) | lp;
            const int idxP = (po << 4) | pp;
            const float la = s_area[idxL];
            const float pa = s_area[idxP];
            num = fmaf(2.f * la, 1.f - (qp + qo) * 0.125f, num);
            den += la + pa;
            if (idxL == 0 || idxL == 255) {  // interior: all 8 labels uniform
                const bool one = (idxL == 255);
                float b = 0.f;
#pragma unroll
                for (int r = 0; r < 4; ++r) {
                    b += __logf(fmaxf(one ? sp[r] : 1.f - sp[r], 1e-12f))
                       + __logf(fmaxf(one ? so[r] : 1.f - so[r], 1e-12f));
                }
                vol -= b;
            }
        };

        const int src = (lane + 63) & 63;    // rotate-down-by-1
        const bool l0 = (lane == 0);
        // carries: rotated e1 state of previous chunk (x = -1 pad for chunk 0)
        float crs[6] = {0.f, 0.f, 0.f, 0.f, 0.f, 0.f};
        float crqA = 0.f, crqB = 0.f; int crb = 0;

#pragma unroll
        for (int c = 0; c < 3; ++c) {
            const int xo = c * 128 + 2 * lane;   // own cols xo, xo+1 (8B-aligned F2)
            float s0[6], s1[6], dq0[6], dq1[6];
            int b0 = 0, b1 = 0;
#pragma unroll
            for (int r = 0; r < 6; ++r) {
                const F2 p2 = *(const F2*)(pred + cbase[r] + xo);
                const I2 l2 = *(const I2*)(labels + cbase[r] + xo);
                float sv0 = sigm(p2.x), sv1 = sigm(p2.y);
                sv0 = rv[r] ? sv0 : 0.f;         // pad after sigmoid -> exactly 0
                sv1 = rv[r] ? sv1 : 0.f;
                const int lm0 = rv[r] ? l2.x : 0;
                const int lm1 = rv[r] ? l2.y : 0;
                s0[r] = sv0; s1[r] = sv1;
                const float d0 = sv0 - (float)lm0, d1 = sv1 - (float)lm1;
                dq0[r] = d0 * d0; dq1[r] = d1 * d1;
                b0 |= (lm0 << r) | ((int)(sv0 > 0.5f) << (8 + r));
                b1 |= (lm1 << r) | ((int)(sv1 > 0.5f) << (8 + r));
            }
            const float qA0 = dq0[0] + dq0[1] + dq0[3] + dq0[4];
            const float qB0 = dq0[1] + dq0[2] + dq0[4] + dq0[5];
            const float qA1 = dq1[0] + dq1[1] + dq1[3] + dq1[4];
            const float qB1 = dq1[1] + dq1[2] + dq1[4] + dq1[5];

            // rotate e1 state: prev col for node x=xo (lane0 chains previous chunk)
            float rs[6]; float rqA, rqB; int rb;
#pragma unroll
            for (int r = 0; r < 6; ++r) {
                const float ro = __shfl(s1[r], src);
                rs[r] = l0 ? crs[r] : ro;
                crs[r] = ro;
            }
            { const float ro = __shfl(qA1, src); rqA = l0 ? crqA : ro; crqA = ro; }
            { const float ro = __shfl(qB1, src); rqB = l0 ? crqB : ro; crqB = ro; }
            { const int   ro = __shfl(b1,  src); rb  = l0 ? crb  : ro; crb  = ro; }

            const float rA[4] = { rs[0], rs[1], rs[3], rs[4] };
            const float rB[4] = { rs[1], rs[2], rs[4], rs[5] };
            const float A0[4] = { s0[0], s0[1], s0[3], s0[4] };
            const float B0[4] = { s0[1], s0[2], s0[4], s0[5] };
            const float A1[4] = { s1[0], s1[1], s1[3], s1[4] };
            const float B1[4] = { s1[1], s1[2], s1[4], s1[5] };

            // node row A (y = 2u): x = xo, xo+1
            node(rA, rqA, nibA(rb), nibA(rb >> 8), A0, qA0, nibA(b0), nibA(b0 >> 8));
            node(A0, qA0, nibA(b0), nibA(b0 >> 8), A1, qA1, nibA(b1), nibA(b1 >> 8));
            if (hasB) {                       // node row B (y = 2u+1)
                node(rB, rqB, nibB(rb), nibB(rb >> 8), B0, qB0, nibB(b0), nibB(b0 >> 8));
                node(B0, qB0, nibB(b0), nibB(b0 >> 8), B1, qB1, nibB(b1), nibB(b1 >> 8));
            }
            if (c == 2 && lane == 63) {       // node x = 384: own col entirely padding
                const float zs[4] = {0.f, 0.f, 0.f, 0.f};
                node(A1, qA1, nibA(b1), nibA(b1 >> 8), zs, 0.f, 0, 0);
                if (hasB)
                    node(B1, qB1, nibB(b1), nibB(b1 >> 8), zs, 0.f, 0, 0);
            }
        }
    }

    // wave + block reduction
#pragma unroll
    for (int off = 32; off > 0; off >>= 1) {
        num += __shfl_down(num, off);
        den += __shfl_down(den, off);
        vol += __shfl_down(vol, off);
    }
    __shared__ float rn[4], rd[4], rvv[4];
    const int w = threadIdx.x >> 6;
    if (lane == 0) { rn[w] = num; rd[w] = den; rvv[w] = vol; }
    __syncthreads();
    if (threadIdx.x == 0) {
        partial[blockIdx.x]              = rn[0] + rn[1] + rn[2] + rn[3];
        partial[BLOCKS + blockIdx.x]     = rd[0] + rd[1] + rd[2] + rd[3];
        partial[2 * BLOCKS + blockIdx.x] = rvv[0] + rvv[1] + rvv[2] + rvv[3];
    }
}

__global__ __launch_bounds__(256) void sd_final(
        const float* __restrict__ partial, float* __restrict__ out)
{
    double n = 0.0, d = 0.0, v = 0.0;
    for (int b = threadIdx.x; b < BLOCKS; b += 256) {
        n += (double)partial[b];
        d += (double)partial[BLOCKS + b];
        v += (double)partial[2 * BLOCKS + b];
    }
#pragma unroll
    for (int off = 32; off > 0; off >>= 1) {
        n += __shfl_down(n, off);
        d += __shfl_down(d, off);
        v += __shfl_down(v, off);
    }
    __shared__ double sn[4], sd_[4], sv[4];
    const int lane = threadIdx.x & 63, w = threadIdx.x >> 6;
    if (lane == 0) { sn[w] = n; sd_[w] = d; sv[w] = v; }
    __syncthreads();
    if (threadIdx.x == 0) {
        const double num = sn[0] + sn[1] + sn[2] + sn[3];
        const double den = sd_[0] + sd_[1] + sd_[2] + sd_[3];
        const double vol = (sv[0] + sv[1] + sv[2] + sv[3]) / (8.0 * (double)NP);
        const double dice = 1.0 - (num + 1e-3) / (den + 1e-3);
        out[0] = (float)(dice + vol);
    }
}

extern "C" void kernel_launch(void* const* d_in, const int* in_sizes, int n_in,
                              void* d_out, int out_size, void* d_ws, size_t ws_size,
                              hipStream_t stream)
{
    const float* pred   = (const float*)d_in[0];
    const int*   labels = (const int*)d_in[1];
    const float* area   = (const float*)d_in[2];
    float* out     = (float*)d_out;
    float* partial = (float*)d_ws;   // 3*BLOCKS floats, fully overwritten each call

    sd_main<<<BLOCKS, 256, 0, stream>>>(pred, labels, area, partial);
    sd_final<<<1, 256, 0, stream>>>(partial, out);
}

// Round 12
// 86.790 us; speedup vs baseline: 1.0142x; 1.0142x over previous
//
#include <hip/hip_runtime.h>
#include <math.h>

// pred: (1,16,384,384) fp32, labels int32 same shape, area fp32[256]
// CHAMPION (R9, 84.7 us): wave-per-node-row, coalesced col=64j+lane ownership,
// rotate-by-1 neighbor exchange, scalar (SGPR) row bases, LDS re-indexed LUT.
// Falsified levers: atomics(R1), ramp(R7), serial chains(R6), occupancy(R8),
// latency exposure(R10), per-wave work(R11). Total is harness-floor dominated
// (268MB ws re-poison at ~78% HBM peak = 43us + restores + dispatch gaps).
constexpr int ZN = 16, YN = 384, XN = 384;
constexpr int NZ = 17, NY = 385, NX = 385;   // node grid
constexpr int NP = NY * NX;                  // 148225 nodes per z-slab
constexpr int NROWS = NZ * NY;               // 6545 node rows, one per wave
constexpr int BLOCKS = (NROWS + 3) / 4;      // 1637 blocks x 4 waves

__device__ __forceinline__ float sigm(float p) {
    return __fdividef(1.f, 1.f + __expf(-p));
}

__global__ __launch_bounds__(256) void sd_main(
        const float* __restrict__ pred,
        const int*   __restrict__ labels,
        const float* __restrict__ area,
        float*       __restrict__ partial)   // [num BLOCKS][den BLOCKS][vol BLOCKS]
{
    // Re-indexed LUT: idx = (own_col_nibble << 4) | prev_col_nibble, nibble bit r = 2dz+dy
    // (original corner k = dz*4+dy*2+dx; dx=0 prev col, dx=1 own col)
    __shared__ float s_area[256];
    {
        const int t = threadIdx.x;
        const int own = t >> 4, prv = t & 15;
        int code = 0;
#pragma unroll
        for (int r = 0; r < 4; ++r)
            code |= (((prv >> r) & 1) << (2 * r)) | (((own >> r) & 1) << (2 * r + 1));
        s_area[t] = area[code];
    }
    __syncthreads();

    const int lane = threadIdx.x & 63;
    // wave-uniform row id in SGPR -> scalar bases, saddr-form loads
    const int wid = __builtin_amdgcn_readfirstlane(blockIdx.x * 4 + (threadIdx.x >> 6));

    float num = 0.f, den = 0.f, vol = 0.f;

    if (wid < NROWS) {
        const int z = wid / NY;              // 0..16   (scalar)
        const int y = wid - z * NY;          // 0..384  (scalar)

        bool rval[4]; int base[4];
#pragma unroll
        for (int r = 0; r < 4; ++r) {
            const int zz = z - 1 + (r >> 1);
            const int yy = y - 1 + (r & 1);
            rval[r] = ((unsigned)zz < (unsigned)ZN) & ((unsigned)yy < (unsigned)YN);
            base[r] = (zz * YN + yy) * XN;   // scalar
        }

        auto node = [&](const float* sp, float qp, int bp,
                        const float* so, float qo, int bo) {
            const int idxL = ((bo & 15) << 4) | (bp & 15);
            const int idxP = (bo & 0xF0) | (bp >> 4);
            const float la = s_area[idxL];
            const float pa = s_area[idxP];
            num = fmaf(2.f * la, 1.f - (qp + qo) * 0.125f, num);
            den += la + pa;
            if (idxL == 0 || idxL == 255) {  // interior: all 8 labels uniform (~0.8%)
                const bool one = (idxL == 255);
                float b = 0.f;
#pragma unroll
                for (int r = 0; r < 4; ++r) {
                    b += __logf(fmaxf(one ? sp[r] : 1.f - sp[r], 1e-12f))
                       + __logf(fmaxf(one ? so[r] : 1.f - so[r], 1e-12f));
                }
                vol -= b;
            }
        };

        const int src = (lane + 63) & 63;    // rotate-down-by-1 source lane
        const bool l0 = (lane == 0);

        // rotated state of previous j-segment (j=-1 -> x=-1 zero padding)
        float rp_s[4] = {0.f, 0.f, 0.f, 0.f};
        float rp_q = 0.f; int rp_b = 0;
        // own state of previous j-segment, for the final node x=384 (lane 63)
        float last_s[4]; float last_q = 0.f; int last_b = 0;

#pragma unroll
        for (int j = 0; j < 6; ++j) {
            const int xo = j * 64 + lane;    // own voxel column; coalesced across lanes
            float s[4] = {0.f, 0.f, 0.f, 0.f};
            float q = 0.f; int b = 0;
#pragma unroll
            for (int r = 0; r < 4; ++r) {
                if (rval[r]) {               // wave-uniform branch
                    const float p = pred[base[r] + xo];
                    const int   l = labels[base[r] + xo];
                    const float sv = sigm(p);
                    s[r] = sv;
                    const float d = sv - (float)l;
                    q = fmaf(d, d, q);
                    b |= (l << r) | ((int)(p > 0.f) << (r + 4));
                }
            }
            // prev-col state: rot[lane] = state[(lane-1)&63]; lane0 takes rot of j-1
            float ps[4], pq; int pb;
#pragma unroll
            for (int r = 0; r < 4; ++r) {
                const float ro = __shfl(s[r], src);
                ps[r] = l0 ? rp_s[r] : ro;
                rp_s[r] = ro;
            }
            {
                const float ro = __shfl(q, src);
                pq = l0 ? rp_q : ro;
                rp_q = ro;
            }
            {
                const int ro = __shfl(b, src);
                pb = l0 ? rp_b : ro;
                rp_b = ro;
            }
            node(ps, pq, pb, s, q, b);
            if (j == 5) {
#pragma unroll
                for (int r = 0; r < 4; ++r) last_s[r] = s[r];
                last_q = q; last_b = b;
            }
        }
        if (lane == 63) {                    // node x=384: prev = col 383, own = padding
            const float zs[4] = {0.f, 0.f, 0.f, 0.f};
            node(last_s, last_q, last_b, zs, 0.f, 0);
        }
    }

    // wave + block reduction
#pragma unroll
    for (int off = 32; off > 0; off >>= 1) {
        num += __shfl_down(num, off);
        den += __shfl_down(den, off);
        vol += __shfl_down(vol, off);
    }
    __shared__ float rn[4], rd[4], rv[4];
    const int w = threadIdx.x >> 6;
    if (lane == 0) { rn[w] = num; rd[w] = den; rv[w] = vol; }
    __syncthreads();
    if (threadIdx.x == 0) {
        partial[blockIdx.x]              = rn[0] + rn[1] + rn[2] + rn[3];
        partial[BLOCKS + blockIdx.x]     = rd[0] + rd[1] + rd[2] + rd[3];
        partial[2 * BLOCKS + blockIdx.x] = rv[0] + rv[1] + rv[2] + rv[3];
    }
}

__global__ __launch_bounds__(256) void sd_final(
        const float* __restrict__ partial, float* __restrict__ out)
{
    double n = 0.0, d = 0.0, v = 0.0;
    for (int b = threadIdx.x; b < BLOCKS; b += 256) {
        n += (double)partial[b];
        d += (double)partial[BLOCKS + b];
        v += (double)partial[2 * BLOCKS + b];
    }
#pragma unroll
    for (int off = 32; off > 0; off >>= 1) {
        n += __shfl_down(n, off);
        d += __shfl_down(d, off);
        v += __shfl_down(v, off);
    }
    __shared__ double sn[4], sd_[4], sv[4];
    const int lane = threadIdx.x & 63, w = threadIdx.x >> 6;
    if (lane == 0) { sn[w] = n; sd_[w] = d; sv[w] = v; }
    __syncthreads();
    if (threadIdx.x == 0) {
        const double num = sn[0] + sn[1] + sn[2] + sn[3];
        const double den = sd_[0] + sd_[1] + sd_[2] + sd_[3];
        const double vol = (sv[0] + sv[1] + sv[2] + sv[3]) / (8.0 * (double)NP);
        const double dice = 1.0 - (num + 1e-3) / (den + 1e-3);
        out[0] = (float)(dice + vol);
    }
}

extern "C" void kernel_launch(void* const* d_in, const int* in_sizes, int n_in,
                              void* d_out, int out_size, void* d_ws, size_t ws_size,
                              hipStream_t stream)
{
    const float* pred   = (const float*)d_in[0];
    const int*   labels = (const int*)d_in[1];
    const float* area   = (const float*)d_in[2];
    float* out     = (float*)d_out;
    float* partial = (float*)d_ws;   // 3*BLOCKS floats, fully overwritten each call

    sd_main<<<BLOCKS, 256, 0, stream>>>(pred, labels, area, partial);
    sd_final<<<1, 256, 0, stream>>>(partial, out);
}